// Round 1
// baseline (530.346 us; speedup 1.0000x reference)
//
#include <hip/hip_runtime.h>

// Rpool (R-MAC): x[16,2048,48,64] fp32 -> out[16,2048,1,1]
// Region grid replicated from _region_coords(48,64,3) at host:
//   idx=0, Wd=1, Hd=0
//   l=1 (wl=48): i in {0},       j in {0,16}
//   l=2 (wl=32): i in {0,16},    j in {0,16,32}
//   l=3 (wl=24): i in {0,12,24}, j in {0,13,26,40}
// + global (full 48x64) = 21 regions.
// Distinct row-windows (start,count): W0=(0,48) W1=(0,32) W2=(16,32)
//                                     W3=(0,24) W4=(12,24) W5=(24,24)

#define BB 16
#define CC 2048
#define HH 48
#define WW 64
#define NREG 21
#define NWIN 6

__constant__ int c_win_r0[NWIN]  = {0, 0, 16, 0, 12, 24};
__constant__ int c_win_cnt[NWIN] = {48, 32, 32, 24, 24, 24};
// region -> (row-window, j0, wl); region 0 = global (rowwin 0, full width)
__constant__ int c_reg_win[NREG] = {0, 0,0, 1,1,1, 2,2,2, 3,3,3,3, 4,4,4,4, 5,5,5,5};
__constant__ int c_reg_j[NREG]   = {0, 0,16, 0,16,32, 0,16,32, 0,13,26,40, 0,13,26,40, 0,13,26,40};
__constant__ int c_reg_wl[NREG]  = {64, 48,48, 32,32,32, 32,32,32, 24,24,24,24, 24,24,24,24, 24,24,24,24};

// Stage 1: one block per (b,c) feature map. Compute 21 region maxes.
__global__ __launch_bounds__(256) void rpool_stage1(const float* __restrict__ x,
                                                    float* __restrict__ R) {
    __shared__ float tile[HH * WW];        // 3072 floats = 12 KB
    __shared__ float colmax[NWIN * WW];    // 384 floats

    const int bid = blockIdx.x;            // b*C + c
    const int t = threadIdx.x;

    // ---- load 48x64 map into LDS, float4-vectorized, fully coalesced ----
    const float4* __restrict__ src = (const float4*)(x + (size_t)bid * (HH * WW));
    float4* dst = (float4*)tile;
    #pragma unroll
    for (int k = 0; k < 3; ++k) {
        dst[t + 256 * k] = src[t + 256 * k];
    }
    __syncthreads();

    // ---- column maxes per row-window: 6 windows x 16 col-quads = 96 tasks ----
    if (t < NWIN * 16) {
        const int quad = t & 15;           // which group of 4 columns
        const int win  = t >> 4;           // which row-window
        const int r0   = c_win_r0[win];
        const int cnt  = c_win_cnt[win];
        const float4* col = (const float4*)tile + quad;   // row stride = 16 float4
        float4 m = col[r0 * 16];
        for (int r = 1; r < cnt; ++r) {
            float4 v = col[(r0 + r) * 16];
            m.x = fmaxf(m.x, v.x);
            m.y = fmaxf(m.y, v.y);
            m.z = fmaxf(m.z, v.z);
            m.w = fmaxf(m.w, v.w);
        }
        ((float4*)colmax)[win * 16 + quad] = m;
    }
    __syncthreads();

    // ---- 21 region maxes from colmax table ----
    if (t < NREG) {
        const int win = c_reg_win[t];
        const int j   = c_reg_j[t];
        const int wl  = c_reg_wl[t];
        const float* cm = colmax + win * WW + j;
        float m = cm[0];
        for (int k = 1; k < wl; ++k) m = fmaxf(m, cm[k]);
        const int b = bid >> 11;           // / 2048
        const int c = bid & 2047;
        R[(((size_t)b * NREG + t) << 11) + c] = m;
    }
}

// Stage 2: one block per batch. Per-region L2-norm over C, sum, final L2-norm.
__global__ __launch_bounds__(256) void rpool_stage2(const float* __restrict__ R,
                                                    float* __restrict__ out) {
    const int b = blockIdx.x;
    const int t = threadIdx.x;
    const int lane = t & 63;
    const int wave = t >> 6;

    __shared__ float partials[NREG][4];
    __shared__ float scale[NREG];
    __shared__ float osq_part[4];

    const float* __restrict__ Rb = R + (size_t)b * NREG * CC;

    // per-region sum of squares over channels
    for (int r = 0; r < NREG; ++r) {
        const float* row = Rb + r * CC;
        float acc = 0.f;
        #pragma unroll
        for (int k = 0; k < CC / 256; ++k) {
            float v = row[t + 256 * k];
            acc += v * v;
        }
        #pragma unroll
        for (int off = 32; off; off >>= 1) acc += __shfl_down(acc, off);
        if (lane == 0) partials[r][wave] = acc;
    }
    __syncthreads();
    if (t < NREG) {
        float s = partials[t][0] + partials[t][1] + partials[t][2] + partials[t][3];
        scale[t] = 1.0f / (sqrtf(s) + 1e-6f);
    }
    __syncthreads();

    // normalized sum over regions + final norm
    float s[CC / 256];
    float osq = 0.f;
    #pragma unroll
    for (int k = 0; k < CC / 256; ++k) {
        const int c = t + 256 * k;
        float acc = 0.f;
        for (int r = 0; r < NREG; ++r) acc += Rb[r * CC + c] * scale[r];
        s[k] = acc;
        osq += acc * acc;
    }
    #pragma unroll
    for (int off = 32; off; off >>= 1) osq += __shfl_down(osq, off);
    if (lane == 0) osq_part[wave] = osq;
    __syncthreads();
    const float tot = osq_part[0] + osq_part[1] + osq_part[2] + osq_part[3];
    const float oscale = 1.0f / (sqrtf(tot) + 1e-6f);
    #pragma unroll
    for (int k = 0; k < CC / 256; ++k) {
        out[(size_t)b * CC + t + 256 * k] = s[k] * oscale;
    }
}

extern "C" void kernel_launch(void* const* d_in, const int* in_sizes, int n_in,
                              void* d_out, int out_size, void* d_ws, size_t ws_size,
                              hipStream_t stream) {
    const float* x = (const float*)d_in[0];
    float* R = (float*)d_ws;               // [16][21][2048] = 2.75 MB scratch
    float* out = (float*)d_out;

    rpool_stage1<<<BB * CC, 256, 0, stream>>>(x, R);
    rpool_stage2<<<BB, 256, 0, stream>>>(R, out);
}